// Round 2
// baseline (314.836 us; speedup 1.0000x reference)
//
#include <hip/hip_runtime.h>

// SpatialDisplConv (separable 12x12 displaced gather-conv)
// B=4 C=3 H=W=512 K=11, input1 padded to 522x522.
// R2: 2D-tiled blocks (32x8 pixels) so the per-block gather footprint
// (~18 KB) fits the 32 KiB L1 -> gather taps become L1 hits.

constexpr int B  = 4;
constexpr int C  = 3;
constexpr int H  = 512;
constexpr int W  = 512;
constexpr int K  = 11;
constexpr int KP = K + 1;              // 12
constexpr int Hp = H + K - 1;          // 522
constexpr int Wp = W + K - 1;          // 522
constexpr int HW = H * W;
constexpr int PLANE1 = Hp * Wp;        // input1 plane per channel

constexpr int TW = 32;                 // tile width  (pixels)
constexpr int TH = 8;                  // tile height (pixels)

__global__ __launch_bounds__(256) void sdc_kernel(
    const float* __restrict__ in1,   // [B][C][Hp][Wp]
    const float* __restrict__ in2,   // [B][K][H][W]
    const float* __restrict__ in3,   // [B][K][H][W]
    const float* __restrict__ in4,   // [B][2][H][W]
    float* __restrict__ out)         // [B][C][H][W]
{
    const int tid = threadIdx.x;
    const int w = blockIdx.x * TW + (tid & (TW - 1));
    const int h = blockIdx.y * TH + (tid >> 5);       // tid/TW, TW=32
    const int b = blockIdx.z;

    const int pix = h * W + w;
    const float dx = in4[(b * 2 + 0) * HW + pix];
    const float dy = in4[(b * 2 + 1) * HW + pix];

    const float py  = (float)h + dy;
    const float px  = (float)w + dx;
    const float fy0 = floorf(py);
    const float fx0 = floorf(px);
    const float wy  = py - fy0;
    const float wx  = px - fx0;
    const int   iy0 = (int)fy0;
    const int   ix0 = (int)fx0;

    // Vy[g] = in2[g]*(1-wy) + in2[g-1]*wy   (g in [0,12), in2[-1]=in2[11]=0)
    float Vy[KP], Hx[KP];
    {
        const float* p2 = in2 + b * K * HW + pix;
        const float* p3 = in3 + b * K * HW + pix;
        float v2[K], v3[K];
        #pragma unroll
        for (int k = 0; k < K; ++k) {
            v2[k] = p2[k * HW];
            v3[k] = p3[k * HW];
        }
        const float omwy = 1.f - wy;
        const float omwx = 1.f - wx;
        #pragma unroll
        for (int g = 0; g < KP; ++g) {
            float a2 = (g < K) ? v2[g] : 0.f;
            float b2 = (g > 0) ? v2[g - 1] : 0.f;
            Vy[g] = a2 * omwy + b2 * wy;
            float a3 = (g < K) ? v3[g] : 0.f;
            float b3 = (g > 0) ? v3[g - 1] : 0.f;
            Hx[g] = a3 * omwx + b3 * wx;
        }
    }

    // Fold column validity into Hx (clamp index, zero weight) — matches
    // reference clip+mask semantics.
    float Hxe[KP];
    int   ixc[KP];
    #pragma unroll
    for (int gx = 0; gx < KP; ++gx) {
        int ix = ix0 + gx;
        bool valid = (ix >= 0) && (ix < Wp);
        Hxe[gx] = valid ? Hx[gx] : 0.f;
        ixc[gx] = valid ? ix : 0;
    }

    float acc0 = 0.f, acc1 = 0.f, acc2 = 0.f;
    const float* base1 = in1 + b * C * PLANE1;

    #pragma unroll 1
    for (int gy = 0; gy < KP; ++gy) {
        int iy = iy0 + gy;
        if (iy < 0 || iy >= Hp) continue;
        const float vy = Vy[gy];
        const float* r = base1 + iy * Wp;
        float s0 = 0.f, s1 = 0.f, s2 = 0.f;
        #pragma unroll
        for (int gx = 0; gx < KP; ++gx) {
            const float hx = Hxe[gx];
            const int   ix = ixc[gx];
            s0 += hx * r[ix];
            s1 += hx * r[PLANE1 + ix];
            s2 += hx * r[2 * PLANE1 + ix];
        }
        acc0 += vy * s0;
        acc1 += vy * s1;
        acc2 += vy * s2;
    }

    float* po = out + b * C * HW + pix;
    po[0]      = acc0;
    po[HW]     = acc1;
    po[2 * HW] = acc2;
}

extern "C" void kernel_launch(void* const* d_in, const int* in_sizes, int n_in,
                              void* d_out, int out_size, void* d_ws, size_t ws_size,
                              hipStream_t stream) {
    const float* in1 = (const float*)d_in[0];
    const float* in2 = (const float*)d_in[1];
    const float* in3 = (const float*)d_in[2];
    const float* in4 = (const float*)d_in[3];
    float* out = (float*)d_out;

    dim3 grid(W / TW, H / TH, B);       // (16, 64, 4)
    dim3 block(TW * TH);                // 256
    sdc_kernel<<<grid, block, 0, stream>>>(in1, in2, in3, in4, out);
}

// Round 3
// 76.101 us; speedup vs baseline: 4.1371x; 4.1371x over previous
//
#include <hip/hip_runtime.h>

// SpatialDisplConv (separable 12x12 displaced gather-conv)
// B=4 C=3 H=W=512 K=11, input1 padded to 522x522.
// R3: LDS-staged gather. Block = 32x8 pixel tile; stage input1 window
// [3][32][64] (24 KB) into LDS, gather via ds_read_b32 with immediate
// offsets off one base vaddr. Per-block min/max displacement reduction
// guards window fit; global-gather fallback otherwise (same semantics).

constexpr int B  = 4;
constexpr int C  = 3;
constexpr int H  = 512;
constexpr int W  = 512;
constexpr int K  = 11;
constexpr int KP = K + 1;              // 12
constexpr int Hp = H + K - 1;          // 522
constexpr int Wp = W + K - 1;          // 522
constexpr int HW = H * W;
constexpr int PLANE1 = Hp * Wp;

constexpr int TW = 32;                 // tile width  (pixels)
constexpr int TH = 8;                  // tile height (pixels)
constexpr int ROWS = 32;               // staged window rows
constexpr int COLS = 64;               // staged window cols
constexpr int CH_STRIDE = ROWS * COLS; // 2048 floats

__global__ __launch_bounds__(256) void sdc_kernel(
    const float* __restrict__ in1,   // [B][C][Hp][Wp]
    const float* __restrict__ in2,   // [B][K][H][W]
    const float* __restrict__ in3,   // [B][K][H][W]
    const float* __restrict__ in4,   // [B][2][H][W]
    float* __restrict__ out)         // [B][C][H][W]
{
    __shared__ float lds[C * ROWS * COLS];   // 24 KB
    __shared__ int   red[16];                // per-wave min/max slots

    const int tid  = threadIdx.x;
    const int lane = tid & 63;
    const int wid  = tid >> 6;
    const int w = blockIdx.x * TW + (tid & (TW - 1));
    const int h = blockIdx.y * TH + (tid >> 5);
    const int b = blockIdx.z;
    const int pix = h * W + w;

    const float dx = in4[(b * 2 + 0) * HW + pix];
    const float dy = in4[(b * 2 + 1) * HW + pix];

    const float py  = (float)h + dy;
    const float px  = (float)w + dx;
    const float fy0 = floorf(py);
    const float fx0 = floorf(px);
    const float wy  = py - fy0;
    const float wx  = px - fx0;
    const int   iy0 = (int)fy0;
    const int   ix0 = (int)fx0;

    // Vy[g] = in2[g]*(1-wy) + in2[g-1]*wy  (in2[-1]=in2[11]=0); same for Hx.
    float Vy[KP], Hx[KP];
    {
        const float* p2 = in2 + b * K * HW + pix;
        const float* p3 = in3 + b * K * HW + pix;
        float v2[K], v3[K];
        #pragma unroll
        for (int k = 0; k < K; ++k) {
            v2[k] = p2[k * HW];
            v3[k] = p3[k * HW];
        }
        const float omwy = 1.f - wy;
        const float omwx = 1.f - wx;
        #pragma unroll
        for (int g = 0; g < KP; ++g) {
            float a2 = (g < K) ? v2[g] : 0.f;
            float b2 = (g > 0) ? v2[g - 1] : 0.f;
            Vy[g] = a2 * omwy + b2 * wy;
            float a3 = (g < K) ? v3[g] : 0.f;
            float b3 = (g > 0) ? v3[g - 1] : 0.f;
            Hx[g] = a3 * omwx + b3 * wx;
        }
    }

    // Fold tap validity into the weights (valid = y_valid & x_valid factors
    // exactly since w = Vy*Hx). Invalid taps then multiply garbage-but-finite
    // staged values by 0.
    float Vye[KP], Hxe[KP];
    #pragma unroll
    for (int g = 0; g < KP; ++g) {
        int iy = iy0 + g;
        Vye[g] = (iy >= 0 && iy < Hp) ? Vy[g] : 0.f;
        int ix = ix0 + g;
        Hxe[g] = (ix >= 0 && ix < Wp) ? Hx[g] : 0.f;
    }

    // Block-wide min/max of iy0, ix0 (wave shfl reduce + LDS combine).
    int mniy = iy0, mxiy = iy0, mnix = ix0, mxix = ix0;
    #pragma unroll
    for (int m = 1; m < 64; m <<= 1) {
        mniy = min(mniy, __shfl_xor(mniy, m, 64));
        mxiy = max(mxiy, __shfl_xor(mxiy, m, 64));
        mnix = min(mnix, __shfl_xor(mnix, m, 64));
        mxix = max(mxix, __shfl_xor(mxix, m, 64));
    }
    if (lane == 0) {
        red[wid * 4 + 0] = mniy;
        red[wid * 4 + 1] = mxiy;
        red[wid * 4 + 2] = mnix;
        red[wid * 4 + 3] = mxix;
    }
    __syncthreads();
    const int row0 = min(min(red[0], red[4]), min(red[8], red[12]));
    const int rmax = max(max(red[1], red[5]), max(red[9], red[13]));
    const int col0 = min(min(red[2], red[6]), min(red[10], red[14]));
    const int cmax = max(max(red[3], red[7]), max(red[11], red[15]));
    const bool fits = (rmax - row0 + KP <= ROWS) && (cmax - col0 + KP <= COLS);

    float acc0 = 0.f, acc1 = 0.f, acc2 = 0.f;

    if (fits) {
        // Cooperative stage: 96 (c,r) rows of 64 cols; wave handles a row,
        // lane = col. Source coords clamped (clamped entries are only ever
        // read by zero-weight taps).
        #pragma unroll
        for (int s = 0; s < C * ROWS / 4; ++s) {
            int sr = s * 4 + wid;                 // 0..95
            int c  = sr >> 5;
            int r  = sr & 31;
            int srcr = min(max(row0 + r, 0), Hp - 1);
            int srcc = min(max(col0 + lane, 0), Wp - 1);
            lds[sr * COLS + lane] = in1[((b * C + c) * Hp + srcr) * Wp + srcc];
        }
        __syncthreads();

        // Gather: single base vaddr, all 432 taps via immediate offsets.
        const float* Lp = lds + (iy0 - row0) * COLS + (ix0 - col0);
        #pragma unroll
        for (int gy = 0; gy < KP; ++gy) {
            float s0 = 0.f, s1 = 0.f, s2 = 0.f;
            #pragma unroll
            for (int gx = 0; gx < KP; ++gx) {
                const float hx = Hxe[gx];
                s0 += hx * Lp[gy * COLS + gx];
                s1 += hx * Lp[CH_STRIDE + gy * COLS + gx];
                s2 += hx * Lp[2 * CH_STRIDE + gy * COLS + gx];
            }
            acc0 += Vye[gy] * s0;
            acc1 += Vye[gy] * s1;
            acc2 += Vye[gy] * s2;
        }
    } else {
        // Fallback: global gather (identical semantics, clamped indices).
        const float* base1 = in1 + b * C * PLANE1;
        #pragma unroll 1
        for (int gy = 0; gy < KP; ++gy) {
            const int iyc = min(max(iy0 + gy, 0), Hp - 1);
            const float* r = base1 + iyc * Wp;
            float s0 = 0.f, s1 = 0.f, s2 = 0.f;
            #pragma unroll
            for (int gx = 0; gx < KP; ++gx) {
                const int ixc = min(max(ix0 + gx, 0), Wp - 1);
                const float hx = Hxe[gx];
                s0 += hx * r[ixc];
                s1 += hx * r[PLANE1 + ixc];
                s2 += hx * r[2 * PLANE1 + ixc];
            }
            acc0 += Vye[gy] * s0;
            acc1 += Vye[gy] * s1;
            acc2 += Vye[gy] * s2;
        }
    }

    float* po = out + b * C * HW + pix;
    po[0]      = acc0;
    po[HW]     = acc1;
    po[2 * HW] = acc2;
}

extern "C" void kernel_launch(void* const* d_in, const int* in_sizes, int n_in,
                              void* d_out, int out_size, void* d_ws, size_t ws_size,
                              hipStream_t stream) {
    const float* in1 = (const float*)d_in[0];
    const float* in2 = (const float*)d_in[1];
    const float* in3 = (const float*)d_in[2];
    const float* in4 = (const float*)d_in[3];
    float* out = (float*)d_out;

    dim3 grid(W / TW, H / TH, B);       // (16, 64, 4)
    dim3 block(TW * TH);                // 256
    sdc_kernel<<<grid, block, 0, stream>>>(in1, in2, in3, in4, out);
}